// Round 9
// baseline (3058.456 us; speedup 1.0000x reference)
//
#include <hip/hip_runtime.h>
#include <hip/hip_bf16.h>

// STDP IF-neuron network, T=50 sequential steps. Persistent-kernel v6.
// x_seq [50,256,1024] f32, weight [2048,1024] f32 -> spike_trace [256,2048] f32.
//
// v5 finding (rounds 4-8): time is CONSTANT ~2890us across spill/no-spill,
// 60..128 VGPR, deep/shallow pipelines. FETCH 409MB / 50 steps at 145 GB/s
// == the step time: each step's 2MB x-slice is first-touched on demand
// inside the serial chain at L3/HBM miss latency; 2 waves/SIMD can't hide
// it and the per-step barrier kills cross-step overlap.
//
// v6 = v5 + CACHE PREFETCH of step t+1's x slice during step t:
//   x(t+1) depends on nothing -> warm it early. Each XCD's 16 blocks
//   (bid%8 == XCD, round-robin dispatch) cover the full 2MB slice:
//   128KB/block = 16 x 16B per thread, kept alive with asm volatile
//   (prevents DCE/sinking). Demand reads next step hit local L2.
// Numerics byte-identical to rounds 4-8 (prefetch is read-only).

#define T_STEPS 50
#define BATCH   256
#define DIM     1024
#define HID     2048
#define HT      16
#define LR_OVER_B (0.005f / 256.0f)

// LDS: wh u16[16][1024] swz | wl u16[16][1024] swz | s u16[16][256] swz
#define SMEM_BYTES (32768 + 32768 + 8192)

typedef __attribute__((ext_vector_type(8))) short short8v;
typedef __attribute__((ext_vector_type(4))) float f32x4;

static __device__ __forceinline__ ushort f32_to_bf16u(float f) {
    __hip_bfloat16 h = __float2bfloat16(f);
    return __builtin_bit_cast(unsigned short, h);
}
static __device__ __forceinline__ float bf16u_to_f32(ushort u) {
    __hip_bfloat16 h = __builtin_bit_cast(__hip_bfloat16, u);
    return __bfloat162float(h);
}

#define MFMA_B16 __builtin_amdgcn_mfma_f32_16x16x32_bf16

// ---------------- prep: row-major + transposed bf16 splits of x -----------
__global__ __launch_bounds__(256) void prep_x(
    const float* __restrict__ x,
    ushort* __restrict__ xh,  ushort* __restrict__ xl,    // [T,B,D]
    ushort* __restrict__ xTh, ushort* __restrict__ xTl)   // [T,D,B]
{
    __shared__ float tile[32][33];
    const int t  = blockIdx.z;
    const int d0 = blockIdx.x * 32;
    const int b0 = blockIdx.y * 32;
    const int tx = threadIdx.x & 31;
    const int ty = threadIdx.x >> 5;         // 0..7
    const float* xt = x + (size_t)t * BATCH * DIM;
    ushort* xht = xh + (size_t)t * BATCH * DIM;
    ushort* xlt = xl + (size_t)t * BATCH * DIM;
#pragma unroll
    for (int r = 0; r < 32; r += 8) {
        size_t gi = (size_t)(b0 + ty + r) * DIM + d0 + tx;
        float v = xt[gi];
        tile[ty + r][tx] = v;
        ushort hi = f32_to_bf16u(v);
        xht[gi] = hi;
        xlt[gi] = f32_to_bf16u(v - bf16u_to_f32(hi));
    }
    __syncthreads();
    ushort* oth = xTh + (size_t)t * DIM * BATCH;
    ushort* otl = xTl + (size_t)t * DIM * BATCH;
#pragma unroll
    for (int r = 0; r < 32; r += 8) {
        float v = tile[tx][ty + r];          // d = d0+ty+r, b = b0+tx
        ushort hi = f32_to_bf16u(v);
        size_t gi = (size_t)(d0 + ty + r) * BATCH + b0 + tx;
        oth[gi] = hi;
        otl[gi] = f32_to_bf16u(v - bf16u_to_f32(hi));
    }
}

// ---------------- THE persistent kernel -----------------------------------
__global__ __launch_bounds__(512, 2) void stdp_persistent(
    const ushort* __restrict__ xh,  const ushort* __restrict__ xl,   // [T,B,D]
    const ushort* __restrict__ xTh, const ushort* __restrict__ xTl,  // [T,D,B]
    const float* __restrict__ weight,                                 // [H,D]
    float* __restrict__ out)                                          // [B,H]
{
    extern __shared__ char smem[];
    ushort* wh = (ushort*)smem;                    // [16][1024] swizzled
    ushort* wl = (ushort*)(smem + 32768);          // [16][1024] swizzled
    ushort* sl = (ushort*)(smem + 65536);          // [16][256]  swizzled

    const int tid  = threadIdx.x;
    const int lane = tid & 63;
    const int w    = tid >> 6;                     // wave 0..7
    const int h0   = blockIdx.x * HT;

    const int fr  = lane & 15;                     // fragment row / h index
    const int kg  = (lane >> 4) * 8;               // fragment k-group offset
    const int rq  = (lane >> 4) * 4;               // D-fragment row base
    const int fsw = (fr & 7) << 3;                 // LDS XOR swizzle

    // prefetch chunk for this block: XCD-coop coverage of next x slice.
    // blocks with bid%8==k land on XCD k (round-robin); the 16 blocks of
    // each XCD (chunk = bid>>3 in 0..15) cover 4 buffers x 4 sub-chunks.
    const int pchunk = (int)(blockIdx.x >> 3);     // 0..15
    const ushort* pfbase =
        (pchunk < 4  ? xh  :
         pchunk < 8  ? xl  :
         pchunk < 12 ? xTh : xTl);
    const size_t pfoff = (size_t)(pchunk & 3) * (BATCH * DIM / 4);  // 128KB chunks

    // ---- init: W master -> registers; bf16 splits -> swizzled LDS ----
    // lane owns h = h0+fr, d = w*128 + tile*16 + rq + {0..3}, tile 0..7
    f32x4 wreg[8];
#pragma unroll
    for (int tile = 0; tile < 8; ++tile) {
        const int d = w * 128 + tile * 16 + rq;
        float4 wv = *(const float4*)&weight[(size_t)(h0 + fr) * DIM + d];
        wreg[tile][0] = wv.x; wreg[tile][1] = wv.y;
        wreg[tile][2] = wv.z; wreg[tile][3] = wv.w;
        ushort4 hi4, lo4;
        ushort* hp = &hi4.x; ushort* lp = &lo4.x;
        const float* p = &wv.x;
#pragma unroll
        for (int e = 0; e < 4; ++e) {
            ushort hb = f32_to_bf16u(p[e]);
            hp[e] = hb;
            lp[e] = f32_to_bf16u(p[e] - bf16u_to_f32(hb));
        }
        const int sidx = (fr << 10) | (d ^ fsw);
        *(ushort4*)&wh[sidx] = hi4;
        *(ushort4*)&wl[sidx] = lo4;
    }
    __syncthreads();

    const f32x4 z4 = {0.f, 0.f, 0.f, 0.f};
    f32x4 vmem[2] = {z4, z4};
    f32x4 trc[2]  = {z4, z4};

    for (int t = 0; t < T_STEPS; ++t) {
        const ushort* xht = xh + (size_t)t * BATCH * DIM;
        const ushort* xlt = xl + (size_t)t * BATCH * DIM;

        // ================= fwd: mem = x @ W^T (3-product split) ===========
        // wave w owns b rows [32w, 32w+32): two sequential 16-b-tile passes.
#pragma unroll
        for (int bt = 0; bt < 2; ++bt) {
            f32x4 acc = z4;
            const size_t r0 = (size_t)(w * 32 + bt * 16 + fr) * DIM + kg;

            short8v GA[4][2];   // single-buffered: 4 k-chunks, hi/lo

#pragma unroll 1
            for (int g = 0; g < 8; ++g) {
                const int kbase = g * 128;
#pragma unroll
                for (int c = 0; c < 4; ++c) {
                    const int kk = kbase + c * 32;
                    GA[c][0] = *(const short8v*)&xht[r0 + kk];
                    GA[c][1] = *(const short8v*)&xlt[r0 + kk];
                }
#pragma unroll
                for (int c = 0; c < 4; ++c) {
                    const int kk = kbase + c * 32;
                    const int bi = (fr << 10) | ((kk + kg) ^ fsw);
                    short8v bh = *(const short8v*)&wh[bi];
                    short8v bl = *(const short8v*)&wl[bi];
                    acc = MFMA_B16(GA[c][0], bh, acc, 0, 0, 0);
                    acc = MFMA_B16(GA[c][0], bl, acc, 0, 0, 0);
                    acc = MFMA_B16(GA[c][1], bh, acc, 0, 0, 0);
                }
            }

            // ---- fused IF update + packed spike store (D: row=b, col=h) --
            const int bb = w * 32 + bt * 16 + rq;
            ushort4 sq; ushort* sp = &sq.x;
#pragma unroll
            for (int j = 0; j < 4; ++j) {
                float nv = vmem[bt][j] + acc[j];
                bool fire = (nv >= 1.0f);
                vmem[bt][j] = fire ? 0.0f : nv;
                trc[bt][j] += fire ? 1.0f : 0.0f;
                sp[j] = fire ? (ushort)0x3F80 : (ushort)0;
            }
            *(ushort4*)&sl[(fr << 8) | (bb ^ fsw)] = sq;
        }

        // ---- cache-warm next step's x slice (this XCD's L2) ----
        // 128KB/block: 512 threads x 16 x 16B, stride 8KB. Loads kept
        // alive by asm volatile (no DCE, no sinking); values unused.
        if (t + 1 < T_STEPS) {
            const short8v* ps =
                (const short8v*)(pfbase + (size_t)(t + 1) * BATCH * DIM + pfoff)
                + tid;
#pragma unroll
            for (int i = 0; i < 16; ++i) {
                short8v p = ps[i * 512];
                asm volatile("" :: "v"(p));
            }
        }

        __syncthreads();   // barrier 1: s complete; fwd W-reads done

        // ================= wupd: dwT = xT @ s^T, W += lr/B * dw ===========
        // wave w owns d rows [128w, 128w+128) = 8 d-tiles of 16.
        if (t < T_STEPS - 1) {
            const ushort* xTht = xTh + (size_t)t * DIM * BATCH;
            const ushort* xTlt = xTl + (size_t)t * DIM * BATCH;

            short8v HA[4][2];   // half-group: 4 b-chunks, hi/lo

#pragma unroll
            for (int tile = 0; tile < 8; ++tile) {
                f32x4 du = z4;
                const size_t drow = (size_t)(w * 128 + tile * 16 + fr) * BATCH;
#pragma unroll 1
                for (int half = 0; half < 2; ++half) {
#pragma unroll
                    for (int c2 = 0; c2 < 4; ++c2) {
                        const size_t gi = drow + (half * 4 + c2) * 32 + kg;
                        HA[c2][0] = *(const short8v*)&xTht[gi];
                        HA[c2][1] = *(const short8v*)&xTlt[gi];
                    }
#pragma unroll
                    for (int c2 = 0; c2 < 4; ++c2) {
                        const int c = half * 4 + c2;
                        short8v sf = *(const short8v*)&sl[(fr << 8) | ((c * 32 + kg) ^ fsw)];
                        du = MFMA_B16(HA[c2][0], sf, du, 0, 0, 0);
                        du = MFMA_B16(HA[c2][1], sf, du, 0, 0, 0);
                    }
                }
                // ---- W update + re-split (D: row=d, col=h=fr) ----
                const int d = w * 128 + tile * 16 + rq;
                ushort4 hi4, lo4;
                ushort* hp = &hi4.x; ushort* lp = &lo4.x;
#pragma unroll
                for (int j = 0; j < 4; ++j) {
                    float wv = fmaf(LR_OVER_B, du[j], wreg[tile][j]);
                    wreg[tile][j] = wv;
                    ushort hb = f32_to_bf16u(wv);
                    hp[j] = hb;
                    lp[j] = f32_to_bf16u(wv - bf16u_to_f32(hb));
                }
                const int si = (fr << 10) | (d ^ fsw);
                *(ushort4*)&wh[si] = hi4;
                *(ushort4*)&wl[si] = lo4;
                // pin scheduling: no cross-tile load hoisting (bounds VGPR
                // liveness; tile loop must stay unrolled for static wreg[])
                __builtin_amdgcn_sched_barrier(0);
            }
        }

        __syncthreads();   // barrier 2: wh/wl consistent for next fwd
    }

    // ---- write trace (registers) to d_out [B,H] ----
#pragma unroll
    for (int bt = 0; bt < 2; ++bt) {
#pragma unroll
        for (int j = 0; j < 4; ++j) {
            int b = w * 32 + bt * 16 + rq + j;
            out[(size_t)b * HID + h0 + fr] = trc[bt][j];
        }
    }
}

// ---------------- fallback fp32 kernels (round-0, small ws) ---------------
#define BK 16
__global__ __launch_bounds__(256) void stdp_fwd_if(
    const float* __restrict__ x, const float* __restrict__ w,
    float* __restrict__ v, float* __restrict__ s, float* __restrict__ trace)
{
    __shared__ float as[BK][64];
    __shared__ float bs[BK][64];
    const int tid = threadIdx.x;
    const int tx = tid & 15, ty = tid >> 4;
    const int b0 = blockIdx.y * 64, h0 = blockIdx.x * 64;
    const int row = tid >> 2, kq = (tid & 3) * 4;
    float acc[4][4] = {};
    for (int k0 = 0; k0 < DIM; k0 += BK) {
        float4 ga = *(const float4*)&x[(size_t)(b0 + row) * DIM + k0 + kq];
        float4 gb = *(const float4*)&w[(size_t)(h0 + row) * DIM + k0 + kq];
        __syncthreads();
        as[kq + 0][row] = ga.x; as[kq + 1][row] = ga.y;
        as[kq + 2][row] = ga.z; as[kq + 3][row] = ga.w;
        bs[kq + 0][row] = gb.x; bs[kq + 1][row] = gb.y;
        bs[kq + 2][row] = gb.z; bs[kq + 3][row] = gb.w;
        __syncthreads();
#pragma unroll
        for (int kk = 0; kk < BK; ++kk) {
            float4 af = *(const float4*)&as[kk][ty * 4];
            float4 bf = *(const float4*)&bs[kk][tx * 4];
            float av[4] = {af.x, af.y, af.z, af.w};
            float bv[4] = {bf.x, bf.y, bf.z, bf.w};
#pragma unroll
            for (int m = 0; m < 4; ++m)
#pragma unroll
                for (int n = 0; n < 4; ++n)
                    acc[m][n] = fmaf(av[m], bv[n], acc[m][n]);
        }
    }
#pragma unroll
    for (int m = 0; m < 4; ++m) {
        size_t idx = (size_t)(b0 + ty * 4 + m) * HID + h0 + tx * 4;
        float4 vv = *(float4*)&v[idx];
        float4 tr = *(float4*)&trace[idx];
        float4 sv;
        float* vvp = &vv.x; float* trp = &tr.x; float* svp = &sv.x;
#pragma unroll
        for (int n = 0; n < 4; ++n) {
            float nv = vvp[n] + acc[m][n];
            float sp = (nv >= 1.0f) ? 1.0f : 0.0f;
            vvp[n] = (nv >= 1.0f) ? 0.0f : nv;
            svp[n] = sp; trp[n] += sp;
        }
        *(float4*)&v[idx] = vv;
        *(float4*)&s[idx] = sv;
        *(float4*)&trace[idx] = tr;
    }
}

__global__ __launch_bounds__(256) void stdp_wupd(
    const float* __restrict__ x, const float* __restrict__ s,
    float* __restrict__ w)
{
    __shared__ float ss[BK][64];
    __shared__ float xs[BK][64];
    const int tid = threadIdx.x;
    const int tx = tid & 15, ty = tid >> 4;
    const int h0 = blockIdx.y * 64, d0 = blockIdx.x * 64;
    const int krow = tid >> 4, c4 = (tid & 15) * 4;
    float acc[4][4] = {};
    for (int bk0 = 0; bk0 < BATCH; bk0 += BK) {
        float4 gs = *(const float4*)&s[(size_t)(bk0 + krow) * HID + h0 + c4];
        float4 gx = *(const float4*)&x[(size_t)(bk0 + krow) * DIM + d0 + c4];
        __syncthreads();
        *(float4*)&ss[krow][c4] = gs;
        *(float4*)&xs[krow][c4] = gx;
        __syncthreads();
#pragma unroll
        for (int kk = 0; kk < BK; ++kk) {
            float4 af = *(const float4*)&ss[kk][ty * 4];
            float4 bf = *(const float4*)&xs[kk][tx * 4];
            float av[4] = {af.x, af.y, af.z, af.w};
            float bv[4] = {bf.x, bf.y, bf.z, bf.w};
#pragma unroll
            for (int m = 0; m < 4; ++m)
#pragma unroll
                for (int n = 0; n < 4; ++n)
                    acc[m][n] = fmaf(av[m], bv[n], acc[m][n]);
        }
    }
#pragma unroll
    for (int m = 0; m < 4; ++m) {
        size_t idx = (size_t)(h0 + ty * 4 + m) * DIM + d0 + tx * 4;
        float4 wv = *(float4*)&w[idx];
        wv.x = fmaf(LR_OVER_B, acc[m][0], wv.x);
        wv.y = fmaf(LR_OVER_B, acc[m][1], wv.y);
        wv.z = fmaf(LR_OVER_B, acc[m][2], wv.z);
        wv.w = fmaf(LR_OVER_B, acc[m][3], wv.w);
        *(float4*)&w[idx] = wv;
    }
}

extern "C" void kernel_launch(void* const* d_in, const int* in_sizes, int n_in,
                              void* d_out, int out_size, void* d_ws, size_t ws_size,
                              hipStream_t stream) {
    (void)in_sizes; (void)n_in;
    const float* x_seq  = (const float*)d_in[0];   // [T, B, D]
    const float* weight = (const float*)d_in[1];   // [H, D]
    float* out = (float*)d_out;                    // [B, H]

    const size_t WN = (size_t)HID * DIM;
    const size_t BH = (size_t)BATCH * HID;
    const size_t XN = (size_t)T_STEPS * BATCH * DIM;  // 13107200

    const size_t need = 4 * XN * 2;                // xh | xl | xTh | xTl

    if (ws_size >= need) {
        ushort* xh  = (ushort*)d_ws;
        ushort* xl  = xh + XN;
        ushort* xTh = xl + XN;
        ushort* xTl = xTh + XN;

        prep_x<<<dim3(DIM / 32, BATCH / 32, T_STEPS), 256, 0, stream>>>(
            x_seq, xh, xl, xTh, xTl);

        hipFuncSetAttribute(reinterpret_cast<const void*>(&stdp_persistent),
                            hipFuncAttributeMaxDynamicSharedMemorySize,
                            SMEM_BYTES);
        stdp_persistent<<<HID / HT, 512, SMEM_BYTES, stream>>>(
            xh, xl, xTh, xTl, weight, out);
    } else {
        // fallback: fp32 VALU path (needs ~12.6 MB)
        float* w = (float*)d_ws;
        float* v = w + WN;
        float* s = v + BH;
        hipMemcpyAsync(w, weight, WN * 4, hipMemcpyDeviceToDevice, stream);
        hipMemsetAsync(v, 0, BH * 4, stream);
        hipMemsetAsync(out, 0, (size_t)out_size * 4, stream);
        dim3 blkA(256), grdA(HID / 64, BATCH / 64);
        dim3 blkB(256), grdB(DIM / 64, HID / 64);
        for (int t = 0; t < T_STEPS; ++t) {
            const float* xt = x_seq + (size_t)t * BATCH * DIM;
            stdp_fwd_if<<<grdA, blkA, 0, stream>>>(xt, w, v, s, out);
            if (t < T_STEPS - 1) {
                stdp_wupd<<<grdB, blkB, 0, stream>>>(xt, s, w);
            }
        }
    }
}

// Round 10
// 1428.951 us; speedup vs baseline: 2.1404x; 2.1404x over previous
//
#include <hip/hip_runtime.h>
#include <hip/hip_bf16.h>

// STDP IF-neuron network, T=50 sequential steps. Persistent-kernel v7.
// x_seq [50,256,1024] f32, weight [2048,1024] f32 -> spike_trace [256,2048] f32.
//
// Rounds 4-9 finding: per-CU ingest was pinned at ~35 GB/s in every
// variant; the wave loads were 16-row scatters (16x64B per instruction).
// v7 repacks x into FRAGMENT-ORDER streams so every wave instruction is a
// dense 1KB line and each wave reads long contiguous runs:
//   XF[t][bt][c][hi/lo][lane*8]  (fwd A-frags,  bt=b-tile, c=k-chunk)
//   XW[t][dt][c][hi/lo][lane*8]  (wupd A-frags, dt=d-tile, c=b-chunk)
// Same values, same MFMA order as rounds 4-9 -> bit-identical output.
// Prefetch (round 9, negative) removed.

#define T_STEPS 50
#define BATCH   256
#define DIM     1024
#define HID     2048
#define HT      16
#define LR_OVER_B (0.005f / 256.0f)

// LDS: wh u16[16][1024] swz | wl u16[16][1024] swz | s u16[16][256] swz
#define SMEM_BYTES (32768 + 32768 + 8192)

typedef __attribute__((ext_vector_type(8))) short short8v;
typedef __attribute__((ext_vector_type(4))) float f32x4;

static __device__ __forceinline__ ushort f32_to_bf16u(float f) {
    __hip_bfloat16 h = __float2bfloat16(f);
    return __builtin_bit_cast(unsigned short, h);
}
static __device__ __forceinline__ float bf16u_to_f32(ushort u) {
    __hip_bfloat16 h = __builtin_bit_cast(__hip_bfloat16, u);
    return __bfloat162float(h);
}

#define MFMA_B16 __builtin_amdgcn_mfma_f32_16x16x32_bf16

// ---------------- prep A: fwd fragment packing ----------------------------
// XF[t][bt=0..15][c=0..31][h=0..1][lane=0..63][8] ushorts.
// Fragment: lane l of b-tile bt, k-chunk c reads
//   x[bt*16 + (l&15)][c*32 + (l>>4)*8 + j], j=0..7.
__global__ __launch_bounds__(256) void prep_fwd(
    const float* __restrict__ x, ushort* __restrict__ XF)
{
    __shared__ float xs[16 * 1024];
    const int t  = blockIdx.x >> 4;
    const int bt = blockIdx.x & 15;
    const float* xrow = x + ((size_t)t * BATCH + bt * 16) * DIM;
    for (int i = threadIdx.x; i < 16 * 1024 / 4; i += 256)
        ((float4*)xs)[i] = ((const float4*)xrow)[i];
    __syncthreads();

    ushort* outb = XF + ((size_t)t * 16 + bt) * (32 * 2 * 512);
    for (int item = threadIdx.x; item < 32 * 64; item += 256) {
        const int c = item >> 6;
        const int l = item & 63;
        const int row = l & 15;
        const int col = c * 32 + (l >> 4) * 8;
        short8v hv, lv;
#pragma unroll
        for (int j = 0; j < 8; ++j) {
            float v = xs[row * 1024 + col + j];
            ushort h = f32_to_bf16u(v);
            hv[j] = (short)h;
            lv[j] = (short)f32_to_bf16u(v - bf16u_to_f32(h));
        }
        *(short8v*)(outb + ((size_t)c * 2 + 0) * 512 + l * 8) = hv;
        *(short8v*)(outb + ((size_t)c * 2 + 1) * 512 + l * 8) = lv;
    }
}

// ---------------- prep B: wupd fragment packing ---------------------------
// XW[t][dt=0..63][c=0..7][h=0..1][lane=0..63][8] ushorts.
// Fragment: lane l of d-tile dt, b-chunk c reads
//   x[c*32 + (l>>4)*8 + j][dt*16 + (l&15)], j=0..7.
__global__ __launch_bounds__(256) void prep_wupd(
    const float* __restrict__ x, ushort* __restrict__ XW)
{
    __shared__ float xs[256 * 16];
    const int t  = blockIdx.x >> 6;
    const int dt = blockIdx.x & 63;
    {
        const int b = threadIdx.x;
        const float* src = x + ((size_t)t * BATCH + b) * DIM + dt * 16;
#pragma unroll
        for (int q = 0; q < 4; ++q)
            ((float4*)&xs[b * 16])[q] = ((const float4*)src)[q];
    }
    __syncthreads();

    ushort* outb = XW + ((size_t)t * 64 + dt) * (8 * 2 * 512);
    for (int item = threadIdx.x; item < 8 * 64; item += 256) {
        const int c = item >> 6;
        const int l = item & 63;
        const int drow = l & 15;
        const int bbase = c * 32 + (l >> 4) * 8;
        short8v hv, lv;
#pragma unroll
        for (int j = 0; j < 8; ++j) {
            float v = xs[(bbase + j) * 16 + drow];
            ushort h = f32_to_bf16u(v);
            hv[j] = (short)h;
            lv[j] = (short)f32_to_bf16u(v - bf16u_to_f32(h));
        }
        *(short8v*)(outb + ((size_t)c * 2 + 0) * 512 + l * 8) = hv;
        *(short8v*)(outb + ((size_t)c * 2 + 1) * 512 + l * 8) = lv;
    }
}

// ---------------- THE persistent kernel -----------------------------------
__global__ __launch_bounds__(512, 2) void stdp_persistent(
    const ushort* __restrict__ XF,   // packed fwd frags
    const ushort* __restrict__ XW,   // packed wupd frags
    const float* __restrict__ weight,                                 // [H,D]
    float* __restrict__ out)                                          // [B,H]
{
    extern __shared__ char smem[];
    ushort* wh = (ushort*)smem;                    // [16][1024] swizzled
    ushort* wl = (ushort*)(smem + 32768);          // [16][1024] swizzled
    ushort* sl = (ushort*)(smem + 65536);          // [16][256]  swizzled

    const int tid  = threadIdx.x;
    const int lane = tid & 63;
    const int w    = tid >> 6;                     // wave 0..7
    const int h0   = blockIdx.x * HT;

    const int fr  = lane & 15;                     // fragment row / h index
    const int kg  = (lane >> 4) * 8;               // fragment k-group offset
    const int rq  = (lane >> 4) * 4;               // D-fragment row base
    const int fsw = (fr & 7) << 3;                 // LDS XOR swizzle

    // ---- init: W master -> registers; bf16 splits -> swizzled LDS ----
    // lane owns h = h0+fr, d = w*128 + tile*16 + rq + {0..3}, tile 0..7
    f32x4 wreg[8];
#pragma unroll
    for (int tile = 0; tile < 8; ++tile) {
        const int d = w * 128 + tile * 16 + rq;
        float4 wv = *(const float4*)&weight[(size_t)(h0 + fr) * DIM + d];
        wreg[tile][0] = wv.x; wreg[tile][1] = wv.y;
        wreg[tile][2] = wv.z; wreg[tile][3] = wv.w;
        ushort4 hi4, lo4;
        ushort* hp = &hi4.x; ushort* lp = &lo4.x;
        const float* p = &wv.x;
#pragma unroll
        for (int e = 0; e < 4; ++e) {
            ushort hb = f32_to_bf16u(p[e]);
            hp[e] = hb;
            lp[e] = f32_to_bf16u(p[e] - bf16u_to_f32(hb));
        }
        const int sidx = (fr << 10) | (d ^ fsw);
        *(ushort4*)&wh[sidx] = hi4;
        *(ushort4*)&wl[sidx] = lo4;
    }
    __syncthreads();

    const f32x4 z4 = {0.f, 0.f, 0.f, 0.f};
    f32x4 vmem[2] = {z4, z4};
    f32x4 trc[2]  = {z4, z4};

    for (int t = 0; t < T_STEPS; ++t) {
        const ushort* xft = XF + (size_t)t * (16 * 32 * 2 * 512);

        // ================= fwd: mem = x @ W^T (3-product split) ===========
        // wave w owns b-tiles {2w, 2w+1}; per tile a dense 64KB stream.
#pragma unroll
        for (int bt = 0; bt < 2; ++bt) {
            f32x4 acc = z4;
            const ushort* wbase = xft + (size_t)(w * 2 + bt) * (32 * 2 * 512)
                                + lane * 8;

            short8v GA[4][2];   // single-buffered: 4 k-chunks, hi/lo

#pragma unroll 1
            for (int g = 0; g < 8; ++g) {
#pragma unroll
                for (int c = 0; c < 4; ++c) {
                    const int cc = g * 4 + c;
                    GA[c][0] = *(const short8v*)(wbase + ((size_t)cc * 2 + 0) * 512);
                    GA[c][1] = *(const short8v*)(wbase + ((size_t)cc * 2 + 1) * 512);
                }
#pragma unroll
                for (int c = 0; c < 4; ++c) {
                    const int kk = (g * 4 + c) * 32;
                    const int bi = (fr << 10) | ((kk + kg) ^ fsw);
                    short8v bh = *(const short8v*)&wh[bi];
                    short8v bl = *(const short8v*)&wl[bi];
                    acc = MFMA_B16(GA[c][0], bh, acc, 0, 0, 0);
                    acc = MFMA_B16(GA[c][0], bl, acc, 0, 0, 0);
                    acc = MFMA_B16(GA[c][1], bh, acc, 0, 0, 0);
                }
            }

            // ---- fused IF update + packed spike store (D: row=b, col=h) --
            const int bb = w * 32 + bt * 16 + rq;
            ushort4 sq; ushort* sp = &sq.x;
#pragma unroll
            for (int j = 0; j < 4; ++j) {
                float nv = vmem[bt][j] + acc[j];
                bool fire = (nv >= 1.0f);
                vmem[bt][j] = fire ? 0.0f : nv;
                trc[bt][j] += fire ? 1.0f : 0.0f;
                sp[j] = fire ? (ushort)0x3F80 : (ushort)0;
            }
            *(ushort4*)&sl[(fr << 8) | (bb ^ fsw)] = sq;
        }

        __syncthreads();   // barrier 1: s complete; fwd W-reads done

        // ================= wupd: dwT = xT @ s^T, W += lr/B * dw ===========
        // wave w owns d-tiles [8w, 8w+8); per tile a dense 16KB stream.
        if (t < T_STEPS - 1) {
            const ushort* xwt = XW + (size_t)t * (64 * 8 * 2 * 512);

            short8v HA[4][2];   // half-group: 4 b-chunks, hi/lo

#pragma unroll
            for (int tile = 0; tile < 8; ++tile) {
                f32x4 du = z4;
                const ushort* tbase = xwt + (size_t)(w * 8 + tile) * (8 * 2 * 512)
                                    + lane * 8;
#pragma unroll 1
                for (int half = 0; half < 2; ++half) {
#pragma unroll
                    for (int c2 = 0; c2 < 4; ++c2) {
                        const int cc = half * 4 + c2;
                        HA[c2][0] = *(const short8v*)(tbase + ((size_t)cc * 2 + 0) * 512);
                        HA[c2][1] = *(const short8v*)(tbase + ((size_t)cc * 2 + 1) * 512);
                    }
#pragma unroll
                    for (int c2 = 0; c2 < 4; ++c2) {
                        const int c = half * 4 + c2;
                        short8v sf = *(const short8v*)&sl[(fr << 8) | ((c * 32 + kg) ^ fsw)];
                        du = MFMA_B16(HA[c2][0], sf, du, 0, 0, 0);
                        du = MFMA_B16(HA[c2][1], sf, du, 0, 0, 0);
                    }
                }
                // ---- W update + re-split (D: row=d, col=h=fr) ----
                const int d = w * 128 + tile * 16 + rq;
                ushort4 hi4, lo4;
                ushort* hp = &hi4.x; ushort* lp = &lo4.x;
#pragma unroll
                for (int j = 0; j < 4; ++j) {
                    float wv = fmaf(LR_OVER_B, du[j], wreg[tile][j]);
                    wreg[tile][j] = wv;
                    ushort hb = f32_to_bf16u(wv);
                    hp[j] = hb;
                    lp[j] = f32_to_bf16u(wv - bf16u_to_f32(hb));
                }
                const int si = (fr << 10) | (d ^ fsw);
                *(ushort4*)&wh[si] = hi4;
                *(ushort4*)&wl[si] = lo4;
                // pin scheduling: no cross-tile load hoisting
                __builtin_amdgcn_sched_barrier(0);
            }
        }

        __syncthreads();   // barrier 2: wh/wl consistent for next fwd
    }

    // ---- write trace (registers) to d_out [B,H] ----
#pragma unroll
    for (int bt = 0; bt < 2; ++bt) {
#pragma unroll
        for (int j = 0; j < 4; ++j) {
            int b = w * 32 + bt * 16 + rq + j;
            out[(size_t)b * HID + h0 + fr] = trc[bt][j];
        }
    }
}

// ---------------- fallback fp32 kernels (round-0, small ws) ---------------
#define BK 16
__global__ __launch_bounds__(256) void stdp_fwd_if(
    const float* __restrict__ x, const float* __restrict__ w,
    float* __restrict__ v, float* __restrict__ s, float* __restrict__ trace)
{
    __shared__ float as[BK][64];
    __shared__ float bs[BK][64];
    const int tid = threadIdx.x;
    const int tx = tid & 15, ty = tid >> 4;
    const int b0 = blockIdx.y * 64, h0 = blockIdx.x * 64;
    const int row = tid >> 2, kq = (tid & 3) * 4;
    float acc[4][4] = {};
    for (int k0 = 0; k0 < DIM; k0 += BK) {
        float4 ga = *(const float4*)&x[(size_t)(b0 + row) * DIM + k0 + kq];
        float4 gb = *(const float4*)&w[(size_t)(h0 + row) * DIM + k0 + kq];
        __syncthreads();
        as[kq + 0][row] = ga.x; as[kq + 1][row] = ga.y;
        as[kq + 2][row] = ga.z; as[kq + 3][row] = ga.w;
        bs[kq + 0][row] = gb.x; bs[kq + 1][row] = gb.y;
        bs[kq + 2][row] = gb.z; bs[kq + 3][row] = gb.w;
        __syncthreads();
#pragma unroll
        for (int kk = 0; kk < BK; ++kk) {
            float4 af = *(const float4*)&as[kk][ty * 4];
            float4 bf = *(const float4*)&bs[kk][tx * 4];
            float av[4] = {af.x, af.y, af.z, af.w};
            float bv[4] = {bf.x, bf.y, bf.z, bf.w};
#pragma unroll
            for (int m = 0; m < 4; ++m)
#pragma unroll
                for (int n = 0; n < 4; ++n)
                    acc[m][n] = fmaf(av[m], bv[n], acc[m][n]);
        }
    }
#pragma unroll
    for (int m = 0; m < 4; ++m) {
        size_t idx = (size_t)(b0 + ty * 4 + m) * HID + h0 + tx * 4;
        float4 vv = *(float4*)&v[idx];
        float4 tr = *(float4*)&trace[idx];
        float4 sv;
        float* vvp = &vv.x; float* trp = &tr.x; float* svp = &sv.x;
#pragma unroll
        for (int n = 0; n < 4; ++n) {
            float nv = vvp[n] + acc[m][n];
            float sp = (nv >= 1.0f) ? 1.0f : 0.0f;
            vvp[n] = (nv >= 1.0f) ? 0.0f : nv;
            svp[n] = sp; trp[n] += sp;
        }
        *(float4*)&v[idx] = vv;
        *(float4*)&s[idx] = sv;
        *(float4*)&trace[idx] = tr;
    }
}

__global__ __launch_bounds__(256) void stdp_wupd(
    const float* __restrict__ x, const float* __restrict__ s,
    float* __restrict__ w)
{
    __shared__ float ss[BK][64];
    __shared__ float xs[BK][64];
    const int tid = threadIdx.x;
    const int tx = tid & 15, ty = tid >> 4;
    const int h0 = blockIdx.y * 64, d0 = blockIdx.x * 64;
    const int krow = tid >> 4, c4 = (tid & 15) * 4;
    float acc[4][4] = {};
    for (int bk0 = 0; bk0 < BATCH; bk0 += BK) {
        float4 gs = *(const float4*)&s[(size_t)(bk0 + krow) * HID + h0 + c4];
        float4 gx = *(const float4*)&x[(size_t)(bk0 + krow) * DIM + d0 + c4];
        __syncthreads();
        *(float4*)&ss[krow][c4] = gs;
        *(float4*)&xs[krow][c4] = gx;
        __syncthreads();
#pragma unroll
        for (int kk = 0; kk < BK; ++kk) {
            float4 af = *(const float4*)&ss[kk][ty * 4];
            float4 bf = *(const float4*)&xs[kk][tx * 4];
            float av[4] = {af.x, af.y, af.z, af.w};
            float bv[4] = {bf.x, bf.y, bf.z, bf.w};
#pragma unroll
            for (int m = 0; m < 4; ++m)
#pragma unroll
                for (int n = 0; n < 4; ++n)
                    acc[m][n] = fmaf(av[m], bv[n], acc[m][n]);
        }
    }
#pragma unroll
    for (int m = 0; m < 4; ++m) {
        size_t idx = (size_t)(h0 + ty * 4 + m) * DIM + d0 + tx * 4;
        float4 wv = *(float4*)&w[idx];
        wv.x = fmaf(LR_OVER_B, acc[m][0], wv.x);
        wv.y = fmaf(LR_OVER_B, acc[m][1], wv.y);
        wv.z = fmaf(LR_OVER_B, acc[m][2], wv.z);
        wv.w = fmaf(LR_OVER_B, acc[m][3], wv.w);
        *(float4*)&w[idx] = wv;
    }
}

extern "C" void kernel_launch(void* const* d_in, const int* in_sizes, int n_in,
                              void* d_out, int out_size, void* d_ws, size_t ws_size,
                              hipStream_t stream) {
    (void)in_sizes; (void)n_in;
    const float* x_seq  = (const float*)d_in[0];   // [T, B, D]
    const float* weight = (const float*)d_in[1];   // [H, D]
    float* out = (float*)d_out;                    // [B, H]

    const size_t WN = (size_t)HID * DIM;
    const size_t BH = (size_t)BATCH * HID;
    const size_t XN = (size_t)T_STEPS * BATCH * DIM;  // 13107200

    // XF: 2*XN ushorts, XW: 2*XN ushorts -> 8*XN bytes total
    const size_t need = 8 * XN;

    if (ws_size >= need) {
        ushort* XF = (ushort*)d_ws;                // 2*XN ushorts
        ushort* XW = XF + 2 * XN;                  // 2*XN ushorts

        prep_fwd<<<T_STEPS * 16, 256, 0, stream>>>(x_seq, XF);
        prep_wupd<<<T_STEPS * 64, 256, 0, stream>>>(x_seq, XW);

        hipFuncSetAttribute(reinterpret_cast<const void*>(&stdp_persistent),
                            hipFuncAttributeMaxDynamicSharedMemorySize,
                            SMEM_BYTES);
        stdp_persistent<<<HID / HT, 512, SMEM_BYTES, stream>>>(
            XF, XW, weight, out);
    } else {
        // fallback: fp32 VALU path (needs ~12.6 MB)
        float* w = (float*)d_ws;
        float* v = w + WN;
        float* s = v + BH;
        hipMemcpyAsync(w, weight, WN * 4, hipMemcpyDeviceToDevice, stream);
        hipMemsetAsync(v, 0, BH * 4, stream);
        hipMemsetAsync(out, 0, (size_t)out_size * 4, stream);
        dim3 blkA(256), grdA(HID / 64, BATCH / 64);
        dim3 blkB(256), grdB(DIM / 64, HID / 64);
        for (int t = 0; t < T_STEPS; ++t) {
            const float* xt = x_seq + (size_t)t * BATCH * DIM;
            stdp_fwd_if<<<grdA, blkA, 0, stream>>>(xt, w, v, s, out);
            if (t < T_STEPS - 1) {
                stdp_wupd<<<grdB, blkB, 0, stream>>>(xt, s, w);
            }
        }
    }
}